// Round 1
// baseline (1383.874 us; speedup 1.0000x reference)
//
#include <hip/hip_runtime.h>
#include <math.h>

#define BB   4
#define CC   512
#define HH   64
#define WW   64
#define NN   4096   // HH*WW
#define TOPK 500

// ---------------------------------------------------------------------------
// Conv 3x3 (SAME, stride 1) + bias + ReLU, fp32 direct.
// Block: 64 out-channels x (4 rows x 64 cols). 256 threads, each 4 rows x 16 co.
// Grid: (co_blocks=8, row_blocks=16, batch=4).
// ---------------------------------------------------------------------------
__global__ __launch_bounds__(256) void conv3x3_relu_kernel(
    const float* __restrict__ x, const float* __restrict__ wgt,
    const float* __restrict__ bias, float* __restrict__ out)
{
    __shared__ float xs[8][6][66];    // [ci][row r0-1+rr][col cc-1]
    __shared__ float wsh[8][9][64];   // [ci][tap][co]
    const int co_base = blockIdx.x * 64;
    const int r0 = blockIdx.y * 4;
    const int b  = blockIdx.z;
    const int tid = threadIdx.x;
    const int col = tid & 63;
    const int co_off = (tid >> 6) * 16;

    float acc[4][16];
#pragma unroll
    for (int r = 0; r < 4; ++r)
#pragma unroll
        for (int k = 0; k < 16; ++k) acc[r][k] = 0.f;

    const float* xb = x + (size_t)b * CC * HH * WW;

    for (int cb = 0; cb < CC; cb += 8) {
        __syncthreads();
        // stage input tile (with halo + zero pad)
        for (int idx = tid; idx < 8 * 6 * 66; idx += 256) {
            int cc = idx % 66;
            int rest = idx / 66;
            int rr = rest % 6;
            int ci = rest / 6;
            int gr = r0 - 1 + rr;
            int gc = cc - 1;
            float v = 0.f;
            if (gr >= 0 && gr < HH && (unsigned)gc < (unsigned)WW)
                v = xb[((cb + ci) * HH + gr) * WW + gc];
            xs[ci][rr][cc] = v;
        }
        // stage weights transposed to [ci][tap][co]
        for (int idx = tid; idx < 8 * 9 * 64; idx += 256) {
            int co = idx & 63;
            int rest = idx >> 6;          // 0..71
            int ci = rest / 9;
            int tap = rest - ci * 9;
            wsh[ci][tap][co] = wgt[(size_t)(co_base + co) * (CC * 9) + (cb + ci) * 9 + tap];
        }
        __syncthreads();
#pragma unroll
        for (int ci = 0; ci < 8; ++ci) {
#pragma unroll
            for (int kh = 0; kh < 3; ++kh) {
                float xv[4][3];
#pragma unroll
                for (int r = 0; r < 4; ++r)
#pragma unroll
                    for (int kw = 0; kw < 3; ++kw)
                        xv[r][kw] = xs[ci][r + kh][col + kw];
#pragma unroll
                for (int kw = 0; kw < 3; ++kw) {
#pragma unroll
                    for (int k = 0; k < 16; k += 4) {
                        float4 wv = *(const float4*)&wsh[ci][kh * 3 + kw][co_off + k];
#pragma unroll
                        for (int r = 0; r < 4; ++r) {
                            acc[r][k + 0] = fmaf(xv[r][kw], wv.x, acc[r][k + 0]);
                            acc[r][k + 1] = fmaf(xv[r][kw], wv.y, acc[r][k + 1]);
                            acc[r][k + 2] = fmaf(xv[r][kw], wv.z, acc[r][k + 2]);
                            acc[r][k + 3] = fmaf(xv[r][kw], wv.w, acc[r][k + 3]);
                        }
                    }
                }
            }
        }
    }
#pragma unroll
    for (int k = 0; k < 16; ++k) {
        const int co = co_base + co_off + k;
        const float bv = bias[co];
#pragma unroll
        for (int r = 0; r < 4; ++r) {
            float v = acc[r][k] + bv;
            v = v > 0.f ? v : 0.f;
            out[(((size_t)b * CC + co) * HH + (r0 + r)) * WW + col] = v;
        }
    }
}

// ---------------------------------------------------------------------------
// 1x1 heads (score + bbox) fused with anchor decode.
// One thread per n; coalesced reads of f[b][ci][n].
// ---------------------------------------------------------------------------
__global__ __launch_bounds__(256) void heads_decode_kernel(
    const float* __restrict__ f, const float* __restrict__ score_w,
    const float* __restrict__ score_b, const float* __restrict__ bbox_w,
    const float* __restrict__ bbox_b,
    float* __restrict__ logits, float* __restrict__ props)
{
    __shared__ float sw[CC];
    __shared__ float bw0[CC], bw1[CC], bw2[CC], bw3[CC];
    const int tid = threadIdx.x;
    for (int i = tid; i < CC; i += 256) {
        sw[i]  = score_w[i];
        bw0[i] = bbox_w[0 * CC + i];
        bw1[i] = bbox_w[1 * CC + i];
        bw2[i] = bbox_w[2 * CC + i];
        bw3[i] = bbox_w[3 * CC + i];
    }
    __syncthreads();
    const int b = blockIdx.y;
    const int n = blockIdx.x * 256 + tid;
    const float* fb = f + (size_t)b * CC * NN + n;
    float s = 0.f, d0 = 0.f, d1 = 0.f, d2 = 0.f, d3 = 0.f;
    for (int ci = 0; ci < CC; ++ci) {
        float v = fb[(size_t)ci * NN];
        s  = fmaf(v, sw[ci],  s);
        d0 = fmaf(v, bw0[ci], d0);
        d1 = fmaf(v, bw1[ci], d1);
        d2 = fmaf(v, bw2[ci], d2);
        d3 = fmaf(v, bw3[ci], d3);
    }
    s  += score_b[0];
    d0 += bbox_b[0]; d1 += bbox_b[1]; d2 += bbox_b[2]; d3 += bbox_b[3];
    logits[b * NN + n] = s;
    // anchors: stride = 800//64 = 12, size 32, centered
    const int hx = n & 63, hy = n >> 6;
    const float cxa = 12.f * (float)hx, cya = 12.f * (float)hy;
    const float cx = d0 * 32.f + cxa;
    const float cy = d1 * 32.f + cya;
    const float w2 = expf(d2) * 16.f;   // 0.5 * exp(dw) * 32
    const float h2 = expf(d3) * 16.f;
    float* p = props + ((size_t)b * NN + n) * 4;
    p[0] = cx - w2; p[1] = cy - h2; p[2] = cx + w2; p[3] = cy + h2;
}

// ---------------------------------------------------------------------------
// Full bitonic sort of 4096 (logit, idx) pairs, descending, ties -> lower idx
// (matches lax.top_k stability). Then gather/clip/sigmoid/valid for top 500.
// One block per batch.
// ---------------------------------------------------------------------------
__global__ __launch_bounds__(1024) void topk_kernel(
    const float* __restrict__ logits, const float* __restrict__ props,
    float* __restrict__ props500, float* __restrict__ probs500,
    unsigned long long* __restrict__ validb)
{
    __shared__ float sv[NN];
    __shared__ int   si[NN];
    const int b = blockIdx.x;
    const int tid = threadIdx.x;
    for (int i = tid; i < NN; i += 1024) { sv[i] = logits[b * NN + i]; si[i] = i; }
    __syncthreads();
    for (int k = 2; k <= NN; k <<= 1) {
        for (int j = k >> 1; j > 0; j >>= 1) {
            for (int t = tid; t < NN / 2; t += 1024) {
                const int i = ((t & ~(j - 1)) << 1) | (t & (j - 1));
                const int l = i | j;
                const float av = sv[i], bv = sv[l];
                const int   ai = si[i], bi = si[l];
                const bool bef  = (av > bv) || (av == bv && ai < bi);
                const bool swap = ((i & k) == 0) ? !bef : bef;
                if (swap) { sv[i] = bv; si[i] = bi; sv[l] = av; si[l] = ai; }
            }
            __syncthreads();
        }
    }
    if (tid < 512) {   // 8 whole waves for ballot
        bool val = false;
        if (tid < TOPK) {
            const int n  = si[tid];
            const float v = sv[tid];
            const float* p = props + ((size_t)b * NN + n) * 4;
            const float x1 = fminf(fmaxf(p[0], 0.f), 800.f);
            const float y1 = fminf(fmaxf(p[1], 0.f), 800.f);
            const float x2 = fminf(fmaxf(p[2], 0.f), 800.f);
            const float y2 = fminf(fmaxf(p[3], 0.f), 800.f);
            const float pr = 1.f / (1.f + expf(-v));
            float* q = props500 + ((size_t)b * TOPK + tid) * 4;
            q[0] = x1; q[1] = y1; q[2] = x2; q[3] = y2;
            probs500[b * TOPK + tid] = pr;
            val = ((x2 - x1) >= 0.001f) && ((y2 - y1) >= 0.001f) && (pr >= 0.f);
        }
        const unsigned long long m = __ballot(val);
        if ((tid & 63) == 0) validb[b * 8 + (tid >> 6)] = m;
    }
}

// ---------------------------------------------------------------------------
// Suppression bitmask: mask[b][i][w] bit j-of-word-w set iff IoU(i,j)>0.7, j>i.
// One thread per (b,i,word).
// ---------------------------------------------------------------------------
__global__ __launch_bounds__(256) void nms_mask_kernel(
    const float* __restrict__ props500, unsigned long long* __restrict__ mask)
{
    const int gid = blockIdx.x * 256 + threadIdx.x;
    if (gid >= BB * TOPK * 8) return;
    const int wword = gid & 7;
    const int rest = gid >> 3;
    const int i = rest % TOPK;
    const int b = rest / TOPK;
    const float* bp = props500 + (size_t)b * TOPK * 4;
    const float x1 = bp[i * 4 + 0], y1 = bp[i * 4 + 1];
    const float x2 = bp[i * 4 + 2], y2 = bp[i * 4 + 3];
    const float ai = (x2 - x1) * (y2 - y1);
    unsigned long long m = 0ull;
    for (int bit = 0; bit < 64; ++bit) {
        const int j = wword * 64 + bit;
        if (j >= TOPK) break;
        if (j <= i) continue;
        const float u1 = bp[j * 4 + 0], v1 = bp[j * 4 + 1];
        const float u2 = bp[j * 4 + 2], v2 = bp[j * 4 + 3];
        const float aj = (u2 - u1) * (v2 - v1);
        const float lx = fmaxf(x1, u1), ly = fmaxf(y1, v1);
        const float rx = fminf(x2, u2), ry = fminf(y2, v2);
        const float iw = fmaxf(rx - lx, 0.f), ih = fmaxf(ry - ly, 0.f);
        const float inter = iw * ih;
        const float iou = inter / (ai + aj - inter + 1e-9f);
        if (iou > 0.7f) m |= (1ull << bit);
    }
    mask[gid] = m;
}

// ---------------------------------------------------------------------------
// Greedy scan over sorted boxes + finalize outputs. One block per batch.
// ---------------------------------------------------------------------------
__global__ __launch_bounds__(256) void nms_finalize_kernel(
    const unsigned long long* __restrict__ mask,
    const unsigned long long* __restrict__ validb,
    const float* __restrict__ props500, const float* __restrict__ probs500,
    float* __restrict__ out_props, float* __restrict__ out_scores,
    float* __restrict__ out_keep)
{
    __shared__ unsigned long long sm[TOPK * 8];
    __shared__ unsigned long long sk[8];
    const int b = blockIdx.x;
    const int tid = threadIdx.x;
    for (int i = tid; i < TOPK * 8; i += 256) sm[i] = mask[(size_t)b * TOPK * 8 + i];
    if (tid < 8) sk[tid] = validb[b * 8 + tid];
    __syncthreads();
    if (tid == 0) {
        unsigned long long kw[8];
#pragma unroll
        for (int w = 0; w < 8; ++w) kw[w] = sk[w];
#pragma unroll
        for (int wi = 0; wi < 8; ++wi) {
            const int lim = (wi == 7) ? (TOPK - 7 * 64) : 64;
            for (int bi = 0; bi < lim; ++bi) {
                const unsigned long long keepbit = (kw[wi] >> bi) & 1ull;
                const unsigned long long sel = 0ull - keepbit;  // branchless: loads prefetchable
                const int i = wi * 64 + bi;
#pragma unroll
                for (int w = 0; w < 8; ++w) kw[w] &= ~(sm[i * 8 + w] & sel);
            }
        }
#pragma unroll
        for (int w = 0; w < 8; ++w) sk[w] = kw[w];
    }
    __syncthreads();
    for (int t = tid; t < TOPK; t += 256) {
        const float fk = (float)((sk[t >> 6] >> (t & 63)) & 1ull);
        const float* q = props500 + ((size_t)b * TOPK + t) * 4;
        float* o = out_props + ((size_t)b * TOPK + t) * 4;
        o[0] = q[0] * fk; o[1] = q[1] * fk; o[2] = q[2] * fk; o[3] = q[3] * fk;
        out_scores[b * TOPK + t] = probs500[b * TOPK + t] * fk;
        out_keep[b * TOPK + t]   = fk;
    }
}

// ---------------------------------------------------------------------------
extern "C" void kernel_launch(void* const* d_in, const int* in_sizes, int n_in,
                              void* d_out, int out_size, void* d_ws, size_t ws_size,
                              hipStream_t stream)
{
    const float* x       = (const float*)d_in[0];
    const float* conv_w  = (const float*)d_in[1];
    const float* conv_b  = (const float*)d_in[2];
    const float* score_w = (const float*)d_in[3];
    const float* score_b = (const float*)d_in[4];
    const float* bbox_w  = (const float*)d_in[5];
    const float* bbox_b  = (const float*)d_in[6];

    float* f_out      = (float*)d_out;
    float* out_props  = f_out + (size_t)BB * CC * HH * WW;   // 8,388,608
    float* out_scores = out_props + BB * TOPK * 4;           // +8,000
    float* out_keep   = out_scores + BB * TOPK;              // +2,000

    // workspace layout (bytes): logits 64K | props 256K | props500 32K |
    // probs500 8K | validb 256B | mask 128K  -> ~496KB total
    float* logits   = (float*)d_ws;                 // BB*NN
    float* props    = logits + BB * NN;             // BB*NN*4
    float* props500 = props + BB * NN * 4;          // BB*TOPK*4
    float* probs500 = props500 + BB * TOPK * 4;     // BB*TOPK
    unsigned long long* validb = (unsigned long long*)(probs500 + BB * TOPK); // 8-byte aligned
    unsigned long long* maskp  = validb + BB * 8;

    conv3x3_relu_kernel<<<dim3(8, 16, BB), 256, 0, stream>>>(x, conv_w, conv_b, f_out);
    heads_decode_kernel<<<dim3(16, BB), 256, 0, stream>>>(f_out, score_w, score_b,
                                                          bbox_w, bbox_b, logits, props);
    topk_kernel<<<BB, 1024, 0, stream>>>(logits, props, props500, probs500, validb);
    nms_mask_kernel<<<(BB * TOPK * 8 + 255) / 256, 256, 0, stream>>>(props500, maskp);
    nms_finalize_kernel<<<BB, 256, 0, stream>>>(maskp, validb, props500, probs500,
                                                out_props, out_scores, out_keep);
}

// Round 3
// 500.370 us; speedup vs baseline: 2.7657x; 2.7657x over previous
//
#include <hip/hip_runtime.h>
#include <math.h>

#define BB   4
#define CC   512
#define HH   64
#define WW   64
#define NN   4096   // HH*WW
#define TOPK 500

typedef _Float16 half8 __attribute__((ext_vector_type(8)));
typedef float f32x16   __attribute__((ext_vector_type(16)));

// Exact 2-level fp16 split of (pre-scaled) fp32: v = h + l + O(2^-24 |v|).
// Operands must be pre-scaled into fp16 normal range (we scale by 2^12).
__device__ __forceinline__ void split_f16(float v, _Float16& h, _Float16& l) {
    h = (_Float16)v;                 // RNE
    l = (_Float16)(v - (float)h);    // v-h exact (Sterbenz), then RNE
}

// ---------------------------------------------------------------------------
// Weight prepack: conv_w fp32 [co][ci][tap] -> (w*4096) fp16 hi/lo,
// layout [tap(9)][cb(32)][co(512)][ci16] (fragment-ready, 16B granules).
// ---------------------------------------------------------------------------
__global__ __launch_bounds__(256) void prepack_w_kernel(
    const float* __restrict__ w, _Float16* __restrict__ wh,
    _Float16* __restrict__ wl)
{
    const int t = blockIdx.x * 256 + threadIdx.x;
    if (t >= 512 * 32) return;
    const int co = t & 511;
    const int cb = t >> 9;
    const float* src = w + (size_t)co * 4608 + cb * 144;  // [ci16][tap9] contiguous
#pragma unroll
    for (int tap = 0; tap < 9; ++tap) {
        half8 h0, h1, l0, l1;
#pragma unroll
        for (int i = 0; i < 8; ++i) {
            _Float16 h, l;
            split_f16(src[i * 9 + tap] * 4096.0f, h, l);
            h0[i] = h; l0[i] = l;
            split_f16(src[(i + 8) * 9 + tap] * 4096.0f, h, l);
            h1[i] = h; l1[i] = l;
        }
        const size_t dst = ((size_t)(tap * 32 + cb) * 512 + co) * 16;
        *(half8*)(wh + dst)     = h0;
        *(half8*)(wh + dst + 8) = h1;
        *(half8*)(wl + dst)     = l0;
        *(half8*)(wl + dst + 8) = l1;
    }
}

// ---------------------------------------------------------------------------
// Conv 3x3 + bias + ReLU via MFMA 32x32x16 f16, hi/lo split (fp32-accurate:
// split residual < 1e-7 rel; only fp32 accumulation noise remains).
// Implicit GEMM: C[co][px] = W[co][k=(tap,ci)] * X[k][px]; both operands
// pre-scaled by 2^12, accumulator carries 2^24, undone in epilogue.
// Block: 128co x 128px (2 image rows). 4 waves 2x2, each 64co x 64px.
// Grid: (co_tiles=4, px_tiles=32, batch=4) = 512 blocks.
// ---------------------------------------------------------------------------
__global__ __launch_bounds__(256) void conv3x3_mfma_kernel(
    const float* __restrict__ x, const _Float16* __restrict__ wh,
    const _Float16* __restrict__ wl, const float* __restrict__ bias,
    float* __restrict__ out)
{
    // ci dim padded 16->24 halves (48B stride: conflict-free, 16B aligned)
    __shared__ __align__(16) _Float16 xs_h[4][66][24];
    __shared__ __align__(16) _Float16 xs_l[4][66][24];

    const int tid  = threadIdx.x;
    const int lane = tid & 63;
    const int wave = tid >> 6;     // 0..3
    const int wco  = wave & 1;     // co half (64)
    const int wpx  = wave >> 1;    // image row within px tile
    const int kg   = lane >> 5;    // k granule (8 ci)
    const int ln   = lane & 31;

    const int co_blk = blockIdx.x * 128;
    const int r0     = blockIdx.y * 2;
    const int b      = blockIdx.z;

    const float* xb = x + (size_t)b * CC * NN;

    // staging decomposition: lanes = ci fastest -> conflict-free LDS writes
    const int s_ci   = tid & 15;
    const int s_sub  = tid >> 4;    // 0..15
    const int s_row  = s_sub & 3;   // 0..3 (rows r0-1..r0+2)
    const int s_colg = s_sub >> 2;  // 0..3 (16-col groups)

    f32x16 acc[2][2];
#pragma unroll
    for (int mt = 0; mt < 2; ++mt)
#pragma unroll
        for (int nt = 0; nt < 2; ++nt)
#pragma unroll
            for (int r = 0; r < 16; ++r) acc[mt][nt][r] = 0.f;

    half8 Ah[2][2], Al[2][2];  // [parity][mt]

    for (int cb = 0; cb < 32; ++cb) {
        // ---- load x slice (16 ci x 4 rows x 64 cols); rows outside -> 0 ----
        const int gr = r0 - 1 + s_row;
        float vals[16];
        if ((unsigned)gr < 64u) {
            const float* p = xb + (size_t)(cb * 16 + s_ci) * NN + gr * 64 + s_colg * 16;
            *(float4*)&vals[0]  = *(const float4*)(p + 0);
            *(float4*)&vals[4]  = *(const float4*)(p + 4);
            *(float4*)&vals[8]  = *(const float4*)(p + 8);
            *(float4*)&vals[12] = *(const float4*)(p + 12);
        } else {
#pragma unroll
            for (int j = 0; j < 16; ++j) vals[j] = 0.f;
        }
        __syncthreads();  // previous round's fragment reads complete
#pragma unroll
        for (int j = 0; j < 16; ++j) {
            _Float16 h, l;
            split_f16(vals[j] * 4096.0f, h, l);
            const int c = 1 + s_colg * 16 + j;
            xs_h[s_row][c][s_ci] = h;
            xs_l[s_row][c][s_ci] = l;
        }
        if (tid < 128) {  // zero halo cols (gc = -1 and 64)
            const int ci = tid & 15, rr = (tid >> 4) & 3, side = (tid >> 6) & 1;
            xs_h[rr][side * 65][ci] = (_Float16)0.f;
            xs_l[rr][side * 65][ci] = (_Float16)0.f;
        }
        __syncthreads();

        // ---- prefetch A for tap 0 ----
        {
            const size_t base = (size_t)(0 * 32 + cb) * 512;
#pragma unroll
            for (int mt = 0; mt < 2; ++mt) {
                const int co_w = co_blk + wco * 64 + mt * 32 + ln;
                const size_t o = (base + co_w) * 16 + kg * 8;
                Ah[0][mt] = *(const half8*)(wh + o);
                Al[0][mt] = *(const half8*)(wl + o);
            }
        }
#pragma unroll
        for (int tap = 0; tap < 9; ++tap) {
            const int pb = tap & 1, pn = pb ^ 1;
            if (tap < 8) {  // prefetch next tap's A fragments
                const size_t base = (size_t)((tap + 1) * 32 + cb) * 512;
#pragma unroll
                for (int mt = 0; mt < 2; ++mt) {
                    const int co_w = co_blk + wco * 64 + mt * 32 + ln;
                    const size_t o = (base + co_w) * 16 + kg * 8;
                    Ah[pn][mt] = *(const half8*)(wh + o);
                    Al[pn][mt] = *(const half8*)(wl + o);
                }
            }
            const int dy = tap / 3, dx = tap % 3;
            half8 Bh[2], Bl[2];
#pragma unroll
            for (int nt = 0; nt < 2; ++nt) {
                const int c = nt * 32 + ln + dx;  // xs col index (gc = c-1)
                Bh[nt] = *(const half8*)&xs_h[wpx + dy][c][kg * 8];
                Bl[nt] = *(const half8*)&xs_l[wpx + dy][c][kg * 8];
            }
#pragma unroll
            for (int mt = 0; mt < 2; ++mt)
#pragma unroll
                for (int nt = 0; nt < 2; ++nt) {
                    acc[mt][nt] = __builtin_amdgcn_mfma_f32_32x32x16_f16(
                        Al[pb][mt], Bh[nt], acc[mt][nt], 0, 0, 0);
                    acc[mt][nt] = __builtin_amdgcn_mfma_f32_32x32x16_f16(
                        Ah[pb][mt], Bl[nt], acc[mt][nt], 0, 0, 0);
                    acc[mt][nt] = __builtin_amdgcn_mfma_f32_32x32x16_f16(
                        Ah[pb][mt], Bh[nt], acc[mt][nt], 0, 0, 0);
                }
        }
    }

    // ---- epilogue: undo 2^24 scale, bias + ReLU, coalesced stores ----
    const float inv_scale = 5.9604644775390625e-08f;  // 2^-24, exact
    const int himg = r0 + wpx;
#pragma unroll
    for (int mt = 0; mt < 2; ++mt)
#pragma unroll
        for (int nt = 0; nt < 2; ++nt) {
            const int wimg = nt * 32 + ln;
#pragma unroll
            for (int reg = 0; reg < 16; ++reg) {
                const int co = co_blk + wco * 64 + mt * 32 +
                               (reg & 3) + 8 * (reg >> 2) + 4 * kg;
                float v = fmaf(acc[mt][nt][reg], inv_scale, bias[co]);
                v = v > 0.f ? v : 0.f;
                out[(((size_t)b * CC + co) * HH + himg) * WW + wimg] = v;
            }
        }
}

// ---------------------------------------------------------------------------
// Fallback fp32 direct conv (used only if ws_size can't hold prepacked weights)
// ---------------------------------------------------------------------------
__global__ __launch_bounds__(256) void conv3x3_relu_kernel(
    const float* __restrict__ x, const float* __restrict__ wgt,
    const float* __restrict__ bias, float* __restrict__ out)
{
    __shared__ float xs[8][6][66];
    __shared__ float wsh[8][9][64];
    const int co_base = blockIdx.x * 64;
    const int r0 = blockIdx.y * 4;
    const int b  = blockIdx.z;
    const int tid = threadIdx.x;
    const int col = tid & 63;
    const int co_off = (tid >> 6) * 16;

    float acc[4][16];
#pragma unroll
    for (int r = 0; r < 4; ++r)
#pragma unroll
        for (int k = 0; k < 16; ++k) acc[r][k] = 0.f;

    const float* xb = x + (size_t)b * CC * HH * WW;

    for (int cb = 0; cb < CC; cb += 8) {
        __syncthreads();
        for (int idx = tid; idx < 8 * 6 * 66; idx += 256) {
            int cc = idx % 66;
            int rest = idx / 66;
            int rr = rest % 6;
            int ci = rest / 6;
            int gr = r0 - 1 + rr;
            int gc = cc - 1;
            float v = 0.f;
            if (gr >= 0 && gr < HH && (unsigned)gc < (unsigned)WW)
                v = xb[((cb + ci) * HH + gr) * WW + gc];
            xs[ci][rr][cc] = v;
        }
        for (int idx = tid; idx < 8 * 9 * 64; idx += 256) {
            int co = idx & 63;
            int rest = idx >> 6;
            int ci = rest / 9;
            int tap = rest - ci * 9;
            wsh[ci][tap][co] = wgt[(size_t)(co_base + co) * (CC * 9) + (cb + ci) * 9 + tap];
        }
        __syncthreads();
#pragma unroll
        for (int ci = 0; ci < 8; ++ci) {
#pragma unroll
            for (int kh = 0; kh < 3; ++kh) {
                float xv[4][3];
#pragma unroll
                for (int r = 0; r < 4; ++r)
#pragma unroll
                    for (int kw = 0; kw < 3; ++kw)
                        xv[r][kw] = xs[ci][r + kh][col + kw];
#pragma unroll
                for (int kw = 0; kw < 3; ++kw) {
#pragma unroll
                    for (int k = 0; k < 16; k += 4) {
                        float4 wv = *(const float4*)&wsh[ci][kh * 3 + kw][co_off + k];
#pragma unroll
                        for (int r = 0; r < 4; ++r) {
                            acc[r][k + 0] = fmaf(xv[r][kw], wv.x, acc[r][k + 0]);
                            acc[r][k + 1] = fmaf(xv[r][kw], wv.y, acc[r][k + 1]);
                            acc[r][k + 2] = fmaf(xv[r][kw], wv.z, acc[r][k + 2]);
                            acc[r][k + 3] = fmaf(xv[r][kw], wv.w, acc[r][k + 3]);
                        }
                    }
                }
            }
        }
    }
#pragma unroll
    for (int k = 0; k < 16; ++k) {
        const int co = co_base + co_off + k;
        const float bv = bias[co];
#pragma unroll
        for (int r = 0; r < 4; ++r) {
            float v = acc[r][k] + bv;
            v = v > 0.f ? v : 0.f;
            out[(((size_t)b * CC + co) * HH + (r0 + r)) * WW + col] = v;
        }
    }
}

// ---------------------------------------------------------------------------
// 1x1 heads (score + bbox) fused with anchor decode.
// ---------------------------------------------------------------------------
__global__ __launch_bounds__(256) void heads_decode_kernel(
    const float* __restrict__ f, const float* __restrict__ score_w,
    const float* __restrict__ score_b, const float* __restrict__ bbox_w,
    const float* __restrict__ bbox_b,
    float* __restrict__ logits, float* __restrict__ props)
{
    __shared__ float sw[CC];
    __shared__ float bw0[CC], bw1[CC], bw2[CC], bw3[CC];
    const int tid = threadIdx.x;
    for (int i = tid; i < CC; i += 256) {
        sw[i]  = score_w[i];
        bw0[i] = bbox_w[0 * CC + i];
        bw1[i] = bbox_w[1 * CC + i];
        bw2[i] = bbox_w[2 * CC + i];
        bw3[i] = bbox_w[3 * CC + i];
    }
    __syncthreads();
    const int b = blockIdx.y;
    const int n = blockIdx.x * 256 + tid;
    const float* fb = f + (size_t)b * CC * NN + n;
    float s = 0.f, d0 = 0.f, d1 = 0.f, d2 = 0.f, d3 = 0.f;
    for (int ci = 0; ci < CC; ++ci) {
        float v = fb[(size_t)ci * NN];
        s  = fmaf(v, sw[ci],  s);
        d0 = fmaf(v, bw0[ci], d0);
        d1 = fmaf(v, bw1[ci], d1);
        d2 = fmaf(v, bw2[ci], d2);
        d3 = fmaf(v, bw3[ci], d3);
    }
    s  += score_b[0];
    d0 += bbox_b[0]; d1 += bbox_b[1]; d2 += bbox_b[2]; d3 += bbox_b[3];
    logits[b * NN + n] = s;
    const int hx = n & 63, hy = n >> 6;
    const float cxa = 12.f * (float)hx, cya = 12.f * (float)hy;
    const float cx = d0 * 32.f + cxa;
    const float cy = d1 * 32.f + cya;
    const float w2 = expf(d2) * 16.f;
    const float h2 = expf(d3) * 16.f;
    float* p = props + ((size_t)b * NN + n) * 4;
    p[0] = cx - w2; p[1] = cy - h2; p[2] = cx + w2; p[3] = cy + h2;
}

// ---------------------------------------------------------------------------
// Bitonic sort (desc, ties -> lower idx) + gather/clip/sigmoid/valid top-500.
// ---------------------------------------------------------------------------
__global__ __launch_bounds__(1024) void topk_kernel(
    const float* __restrict__ logits, const float* __restrict__ props,
    float* __restrict__ props500, float* __restrict__ probs500,
    unsigned long long* __restrict__ validb)
{
    __shared__ float sv[NN];
    __shared__ int   si[NN];
    const int b = blockIdx.x;
    const int tid = threadIdx.x;
    for (int i = tid; i < NN; i += 1024) { sv[i] = logits[b * NN + i]; si[i] = i; }
    __syncthreads();
    for (int k = 2; k <= NN; k <<= 1) {
        for (int j = k >> 1; j > 0; j >>= 1) {
            for (int t = tid; t < NN / 2; t += 1024) {
                const int i = ((t & ~(j - 1)) << 1) | (t & (j - 1));
                const int l = i | j;
                const float av = sv[i], bv = sv[l];
                const int   ai = si[i], bi = si[l];
                const bool bef  = (av > bv) || (av == bv && ai < bi);
                const bool swap = ((i & k) == 0) ? !bef : bef;
                if (swap) { sv[i] = bv; si[i] = bi; sv[l] = av; si[l] = ai; }
            }
            __syncthreads();
        }
    }
    if (tid < 512) {
        bool val = false;
        if (tid < TOPK) {
            const int n  = si[tid];
            const float v = sv[tid];
            const float* p = props + ((size_t)b * NN + n) * 4;
            const float x1 = fminf(fmaxf(p[0], 0.f), 800.f);
            const float y1 = fminf(fmaxf(p[1], 0.f), 800.f);
            const float x2 = fminf(fmaxf(p[2], 0.f), 800.f);
            const float y2 = fminf(fmaxf(p[3], 0.f), 800.f);
            const float pr = 1.f / (1.f + expf(-v));
            float* q = props500 + ((size_t)b * TOPK + tid) * 4;
            q[0] = x1; q[1] = y1; q[2] = x2; q[3] = y2;
            probs500[b * TOPK + tid] = pr;
            val = ((x2 - x1) >= 0.001f) && ((y2 - y1) >= 0.001f) && (pr >= 0.f);
        }
        const unsigned long long m = __ballot(val);
        if ((tid & 63) == 0) validb[b * 8 + (tid >> 6)] = m;
    }
}

// ---------------------------------------------------------------------------
__global__ __launch_bounds__(256) void nms_mask_kernel(
    const float* __restrict__ props500, unsigned long long* __restrict__ mask)
{
    const int gid = blockIdx.x * 256 + threadIdx.x;
    if (gid >= BB * TOPK * 8) return;
    const int wword = gid & 7;
    const int rest = gid >> 3;
    const int i = rest % TOPK;
    const int b = rest / TOPK;
    const float* bp = props500 + (size_t)b * TOPK * 4;
    const float x1 = bp[i * 4 + 0], y1 = bp[i * 4 + 1];
    const float x2 = bp[i * 4 + 2], y2 = bp[i * 4 + 3];
    const float ai = (x2 - x1) * (y2 - y1);
    unsigned long long m = 0ull;
    for (int bit = 0; bit < 64; ++bit) {
        const int j = wword * 64 + bit;
        if (j >= TOPK) break;
        if (j <= i) continue;
        const float u1 = bp[j * 4 + 0], v1 = bp[j * 4 + 1];
        const float u2 = bp[j * 4 + 2], v2 = bp[j * 4 + 3];
        const float aj = (u2 - u1) * (v2 - v1);
        const float lx = fmaxf(x1, u1), ly = fmaxf(y1, v1);
        const float rx = fminf(x2, u2), ry = fminf(y2, v2);
        const float iw = fmaxf(rx - lx, 0.f), ih = fmaxf(ry - ly, 0.f);
        const float inter = iw * ih;
        const float iou = inter / (ai + aj - inter + 1e-9f);
        if (iou > 0.7f) m |= (1ull << bit);
    }
    mask[gid] = m;
}

// ---------------------------------------------------------------------------
__global__ __launch_bounds__(256) void nms_finalize_kernel(
    const unsigned long long* __restrict__ mask,
    const unsigned long long* __restrict__ validb,
    const float* __restrict__ props500, const float* __restrict__ probs500,
    float* __restrict__ out_props, float* __restrict__ out_scores,
    float* __restrict__ out_keep)
{
    __shared__ unsigned long long sm[TOPK * 8];
    __shared__ unsigned long long sk[8];
    const int b = blockIdx.x;
    const int tid = threadIdx.x;
    for (int i = tid; i < TOPK * 8; i += 256) sm[i] = mask[(size_t)b * TOPK * 8 + i];
    if (tid < 8) sk[tid] = validb[b * 8 + tid];
    __syncthreads();
    if (tid == 0) {
        unsigned long long kw[8];
#pragma unroll
        for (int w = 0; w < 8; ++w) kw[w] = sk[w];
#pragma unroll
        for (int wi = 0; wi < 8; ++wi) {
            const int lim = (wi == 7) ? (TOPK - 7 * 64) : 64;
            for (int bi = 0; bi < lim; ++bi) {
                const unsigned long long keepbit = (kw[wi] >> bi) & 1ull;
                const unsigned long long sel = 0ull - keepbit;
                const int i = wi * 64 + bi;
#pragma unroll
                for (int w = 0; w < 8; ++w) kw[w] &= ~(sm[i * 8 + w] & sel);
            }
        }
#pragma unroll
        for (int w = 0; w < 8; ++w) sk[w] = kw[w];
    }
    __syncthreads();
    for (int t = tid; t < TOPK; t += 256) {
        const float fk = (float)((sk[t >> 6] >> (t & 63)) & 1ull);
        const float* q = props500 + ((size_t)b * TOPK + t) * 4;
        float* o = out_props + ((size_t)b * TOPK + t) * 4;
        o[0] = q[0] * fk; o[1] = q[1] * fk; o[2] = q[2] * fk; o[3] = q[3] * fk;
        out_scores[b * TOPK + t] = probs500[b * TOPK + t] * fk;
        out_keep[b * TOPK + t]   = fk;
    }
}

// ---------------------------------------------------------------------------
extern "C" void kernel_launch(void* const* d_in, const int* in_sizes, int n_in,
                              void* d_out, int out_size, void* d_ws, size_t ws_size,
                              hipStream_t stream)
{
    const float* x       = (const float*)d_in[0];
    const float* conv_w  = (const float*)d_in[1];
    const float* conv_b  = (const float*)d_in[2];
    const float* score_w = (const float*)d_in[3];
    const float* score_b = (const float*)d_in[4];
    const float* bbox_w  = (const float*)d_in[5];
    const float* bbox_b  = (const float*)d_in[6];

    float* f_out      = (float*)d_out;
    float* out_props  = f_out + (size_t)BB * CC * HH * WW;
    float* out_scores = out_props + BB * TOPK * 4;
    float* out_keep   = out_scores + BB * TOPK;

    const size_t WPE = (size_t)9 * 32 * 512 * 16;            // halves per wp buffer
    const size_t WP_BYTES = WPE * 2 * sizeof(_Float16);      // hi+lo
    const size_t SCRATCH_BYTES =
        (size_t)BB * NN * 4 + (size_t)BB * NN * 16 + (size_t)BB * TOPK * 16 +
        (size_t)BB * TOPK * 4 + (size_t)BB * 8 * 8 + (size_t)BB * TOPK * 8 * 8 + 256;
    const bool use_mfma = (ws_size >= WP_BYTES + SCRATCH_BYTES);

    _Float16* wph = (_Float16*)d_ws;
    _Float16* wpl = wph + WPE;
    char* scratch = use_mfma ? (char*)(wpl + WPE) : (char*)d_ws;

    float* logits   = (float*)scratch;
    float* props    = logits + BB * NN;
    float* props500 = props + BB * NN * 4;
    float* probs500 = props500 + BB * TOPK * 4;
    unsigned long long* validb = (unsigned long long*)(probs500 + BB * TOPK);
    unsigned long long* maskp  = validb + BB * 8;

    if (use_mfma) {
        prepack_w_kernel<<<64, 256, 0, stream>>>(conv_w, wph, wpl);
        conv3x3_mfma_kernel<<<dim3(4, 32, BB), 256, 0, stream>>>(x, wph, wpl, conv_b, f_out);
    } else {
        conv3x3_relu_kernel<<<dim3(8, 16, BB), 256, 0, stream>>>(x, conv_w, conv_b, f_out);
    }
    heads_decode_kernel<<<dim3(16, BB), 256, 0, stream>>>(f_out, score_w, score_b,
                                                          bbox_w, bbox_b, logits, props);
    topk_kernel<<<BB, 1024, 0, stream>>>(logits, props, props500, probs500, validb);
    nms_mask_kernel<<<(BB * TOPK * 8 + 255) / 256, 256, 0, stream>>>(props500, maskp);
    nms_finalize_kernel<<<BB, 256, 0, stream>>>(maskp, validb, props500, probs500,
                                                out_props, out_scores, out_keep);
}

// Round 4
// 458.021 us; speedup vs baseline: 3.0214x; 1.0925x over previous
//
#include <hip/hip_runtime.h>
#include <math.h>

#define BB   4
#define CC   512
#define HH   64
#define WW   64
#define NN   4096   // HH*WW
#define TOPK 500

typedef _Float16 half8 __attribute__((ext_vector_type(8)));
typedef float f32x16   __attribute__((ext_vector_type(16)));

// Exact 2-level fp16 split of (pre-scaled) fp32: v = h + l + O(2^-24 |v|).
__device__ __forceinline__ void split_f16(float v, _Float16& h, _Float16& l) {
    h = (_Float16)v;                 // RNE
    l = (_Float16)(v - (float)h);    // v-h exact (Sterbenz), then RNE
}

// ---------------------------------------------------------------------------
// Weight prepack: conv_w fp32 [co][ci][tap] -> (w*4096) fp16 hi/lo,
// layout [tap(9)][cb(32)][co(512)][ci16] (fragment-ready, 16B granules).
// ---------------------------------------------------------------------------
__global__ __launch_bounds__(256) void prepack_w_kernel(
    const float* __restrict__ w, _Float16* __restrict__ wh,
    _Float16* __restrict__ wl)
{
    const int t = blockIdx.x * 256 + threadIdx.x;
    if (t >= 512 * 32) return;
    const int co = t & 511;
    const int cb = t >> 9;
    const float* src = w + (size_t)co * 4608 + cb * 144;  // [ci16][tap9] contiguous
#pragma unroll
    for (int tap = 0; tap < 9; ++tap) {
        half8 h0, h1, l0, l1;
#pragma unroll
        for (int i = 0; i < 8; ++i) {
            _Float16 h, l;
            split_f16(src[i * 9 + tap] * 4096.0f, h, l);
            h0[i] = h; l0[i] = l;
            split_f16(src[(i + 8) * 9 + tap] * 4096.0f, h, l);
            h1[i] = h; l1[i] = l;
        }
        const size_t dst = ((size_t)(tap * 32 + cb) * 512 + co) * 16;
        *(half8*)(wh + dst)     = h0;
        *(half8*)(wh + dst + 8) = h1;
        *(half8*)(wl + dst)     = l0;
        *(half8*)(wl + dst + 8) = l1;
    }
}

// ---------------------------------------------------------------------------
// Conv 3x3 + bias + ReLU via MFMA 32x32x16 f16, hi/lo split (fp32-accurate).
// Tile identical to validated R3 version (128co x 128px, 4 waves 2x2 of
// 64co x 64px). New: double-buffered LDS (1 barrier/cb), B prefetched one
// tap ahead, next-cb global loads issued at tap 7 (after last A prefetch so
// the in-order vmcnt queue lets A complete without draining them).
// ---------------------------------------------------------------------------
__global__ __launch_bounds__(256, 2) void conv3x3_mfma_kernel(
    const float* __restrict__ x, const _Float16* __restrict__ wh,
    const _Float16* __restrict__ wl, const float* __restrict__ bias,
    float* __restrict__ out)
{
    // ci dim padded 16->24 halves (48B stride: conflict-free, 16B aligned)
    __shared__ __align__(16) _Float16 xs_h[2][4][66][24];
    __shared__ __align__(16) _Float16 xs_l[2][4][66][24];

    const int tid  = threadIdx.x;
    const int lane = tid & 63;
    const int wave = tid >> 6;     // 0..3
    const int wco  = wave & 1;     // co half (64)
    const int wpx  = wave >> 1;    // image row within px tile
    const int kg   = lane >> 5;    // k granule (8 ci)
    const int ln   = lane & 31;

    const int co_blk = blockIdx.x * 128;
    const int r0     = blockIdx.y * 2;
    const int b      = blockIdx.z;

    const float* xb = x + (size_t)b * CC * NN;

    // staging decomposition: lanes = ci fastest -> conflict-free LDS writes
    const int s_ci   = tid & 15;
    const int s_sub  = tid >> 4;    // 0..15
    const int s_row  = s_sub & 3;   // 0..3 (rows r0-1..r0+2)
    const int s_colg = s_sub >> 2;  // 0..3 (16-col groups)
    const int gr     = r0 - 1 + s_row;
    const bool gr_ok = ((unsigned)gr < 64u);
    const float* xrow = xb + (size_t)s_ci * NN + gr * 64 + s_colg * 16;

    // zero halo cols (gc = -1 and 64) once, both buffers
    if (tid < 128) {
        const int ci = tid & 15, rr = (tid >> 4) & 3, side = (tid >> 6) & 1;
        xs_h[0][rr][side * 65][ci] = (_Float16)0.f;
        xs_l[0][rr][side * 65][ci] = (_Float16)0.f;
        xs_h[1][rr][side * 65][ci] = (_Float16)0.f;
        xs_l[1][rr][side * 65][ci] = (_Float16)0.f;
    }

    f32x16 acc[2][2];
#pragma unroll
    for (int mt = 0; mt < 2; ++mt)
#pragma unroll
        for (int nt = 0; nt < 2; ++nt)
#pragma unroll
            for (int r = 0; r < 16; ++r) acc[mt][nt][r] = 0.f;

    half8 Ah[2][2], Al[2][2];  // [parity][mt]
    half8 Bh[2][2], Bl[2][2];  // [parity][nt]

    // A element offsets within a (tap,cb) slab of 8192 halves
    const int co_w0  = co_blk + wco * 64 + ln;
    const size_t aoff0 = (size_t)co_w0 * 16 + kg * 8;
    const size_t aoff1 = aoff0 + 32 * 16;

    float vals[16];
#pragma unroll
    for (int j = 0; j < 16; ++j) vals[j] = 0.f;

    // ---- preload + stage cb=0 ----
    if (gr_ok) {
        *(float4*)&vals[0]  = *(const float4*)(xrow + 0);
        *(float4*)&vals[4]  = *(const float4*)(xrow + 4);
        *(float4*)&vals[8]  = *(const float4*)(xrow + 8);
        *(float4*)&vals[12] = *(const float4*)(xrow + 12);
    }
#pragma unroll
    for (int j = 0; j < 16; ++j) {
        _Float16 h, l;
        split_f16(vals[j] * 4096.0f, h, l);
        const int c = 1 + s_colg * 16 + j;
        xs_h[0][s_row][c][s_ci] = h;
        xs_l[0][s_row][c][s_ci] = l;
    }
    __syncthreads();
    int buf = 0;

    for (int cb = 0; cb < 32; ++cb) {
        // ---- prefetch tap 0 A (global) and B (LDS) into parity 0 ----
        {
            const size_t ab = (size_t)(0 * 32 + cb) * 8192;
            Ah[0][0] = *(const half8*)(wh + ab + aoff0);
            Al[0][0] = *(const half8*)(wl + ab + aoff0);
            Ah[0][1] = *(const half8*)(wh + ab + aoff1);
            Al[0][1] = *(const half8*)(wl + ab + aoff1);
            Bh[0][0] = *(const half8*)&xs_h[buf][wpx][ln][kg * 8];
            Bl[0][0] = *(const half8*)&xs_l[buf][wpx][ln][kg * 8];
            Bh[0][1] = *(const half8*)&xs_h[buf][wpx][32 + ln][kg * 8];
            Bl[0][1] = *(const half8*)&xs_l[buf][wpx][32 + ln][kg * 8];
        }
#pragma unroll
        for (int tap = 0; tap < 9; ++tap) {
            const int pb = tap & 1, pn = pb ^ 1;
            if (tap < 8) {  // prefetch next tap's fragments
                const int t1 = tap + 1;
                const size_t ab = (size_t)(t1 * 32 + cb) * 8192;
                Ah[pn][0] = *(const half8*)(wh + ab + aoff0);
                Al[pn][0] = *(const half8*)(wl + ab + aoff0);
                Ah[pn][1] = *(const half8*)(wh + ab + aoff1);
                Al[pn][1] = *(const half8*)(wl + ab + aoff1);
                const int dy1 = t1 / 3, dx1 = t1 % 3;
                Bh[pn][0] = *(const half8*)&xs_h[buf][wpx + dy1][ln + dx1][kg * 8];
                Bl[pn][0] = *(const half8*)&xs_l[buf][wpx + dy1][ln + dx1][kg * 8];
                Bh[pn][1] = *(const half8*)&xs_h[buf][wpx + dy1][32 + ln + dx1][kg * 8];
                Bl[pn][1] = *(const half8*)&xs_l[buf][wpx + dy1][32 + ln + dx1][kg * 8];
            }
            if (tap == 7 && cb < 31 && gr_ok) {
                // issue next cb's staging loads AFTER the last A prefetch:
                // in-order vmcnt lets tap-8 A complete without draining these
                const float* p = xrow + (size_t)(cb + 1) * 16 * NN;
                *(float4*)&vals[0]  = *(const float4*)(p + 0);
                *(float4*)&vals[4]  = *(const float4*)(p + 4);
                *(float4*)&vals[8]  = *(const float4*)(p + 8);
                *(float4*)&vals[12] = *(const float4*)(p + 12);
            }
#pragma unroll
            for (int mt = 0; mt < 2; ++mt)
#pragma unroll
                for (int nt = 0; nt < 2; ++nt) {
                    acc[mt][nt] = __builtin_amdgcn_mfma_f32_32x32x16_f16(
                        Al[pb][mt], Bh[pb][nt], acc[mt][nt], 0, 0, 0);
                    acc[mt][nt] = __builtin_amdgcn_mfma_f32_32x32x16_f16(
                        Ah[pb][mt], Bl[pb][nt], acc[mt][nt], 0, 0, 0);
                    acc[mt][nt] = __builtin_amdgcn_mfma_f32_32x32x16_f16(
                        Ah[pb][mt], Bh[pb][nt], acc[mt][nt], 0, 0, 0);
                }
        }
        // ---- stage cb+1 into the other buffer; single barrier per cb ----
        if (cb < 31) {
            const int nb = buf ^ 1;
#pragma unroll
            for (int j = 0; j < 16; ++j) {
                _Float16 h, l;
                split_f16(vals[j] * 4096.0f, h, l);
                const int c = 1 + s_colg * 16 + j;
                xs_h[nb][s_row][c][s_ci] = h;
                xs_l[nb][s_row][c][s_ci] = l;
            }
            __syncthreads();
            buf = nb;
        }
    }

    // ---- epilogue: undo 2^24 scale, bias + ReLU, coalesced stores ----
    const float inv_scale = 5.9604644775390625e-08f;  // 2^-24, exact
    const int himg = r0 + wpx;
#pragma unroll
    for (int mt = 0; mt < 2; ++mt)
#pragma unroll
        for (int nt = 0; nt < 2; ++nt) {
            const int wimg = nt * 32 + ln;
#pragma unroll
            for (int reg = 0; reg < 16; ++reg) {
                const int co = co_blk + wco * 64 + mt * 32 +
                               (reg & 3) + 8 * (reg >> 2) + 4 * kg;
                float v = fmaf(acc[mt][nt][reg], inv_scale, bias[co]);
                v = v > 0.f ? v : 0.f;
                out[(((size_t)b * CC + co) * HH + himg) * WW + wimg] = v;
            }
        }
}

// ---------------------------------------------------------------------------
// Fallback fp32 direct conv (used only if ws_size can't hold prepacked weights)
// ---------------------------------------------------------------------------
__global__ __launch_bounds__(256) void conv3x3_relu_kernel(
    const float* __restrict__ x, const float* __restrict__ wgt,
    const float* __restrict__ bias, float* __restrict__ out)
{
    __shared__ float xs[8][6][66];
    __shared__ float wsh[8][9][64];
    const int co_base = blockIdx.x * 64;
    const int r0 = blockIdx.y * 4;
    const int b  = blockIdx.z;
    const int tid = threadIdx.x;
    const int col = tid & 63;
    const int co_off = (tid >> 6) * 16;

    float acc[4][16];
#pragma unroll
    for (int r = 0; r < 4; ++r)
#pragma unroll
        for (int k = 0; k < 16; ++k) acc[r][k] = 0.f;

    const float* xb = x + (size_t)b * CC * HH * WW;

    for (int cb = 0; cb < CC; cb += 8) {
        __syncthreads();
        for (int idx = tid; idx < 8 * 6 * 66; idx += 256) {
            int cc = idx % 66;
            int rest = idx / 66;
            int rr = rest % 6;
            int ci = rest / 6;
            int gr = r0 - 1 + rr;
            int gc = cc - 1;
            float v = 0.f;
            if (gr >= 0 && gr < HH && (unsigned)gc < (unsigned)WW)
                v = xb[((cb + ci) * HH + gr) * WW + gc];
            xs[ci][rr][cc] = v;
        }
        for (int idx = tid; idx < 8 * 9 * 64; idx += 256) {
            int co = idx & 63;
            int rest = idx >> 6;
            int ci = rest / 9;
            int tap = rest - ci * 9;
            wsh[ci][tap][co] = wgt[(size_t)(co_base + co) * (CC * 9) + (cb + ci) * 9 + tap];
        }
        __syncthreads();
#pragma unroll
        for (int ci = 0; ci < 8; ++ci) {
#pragma unroll
            for (int kh = 0; kh < 3; ++kh) {
                float xv[4][3];
#pragma unroll
                for (int r = 0; r < 4; ++r)
#pragma unroll
                    for (int kw = 0; kw < 3; ++kw)
                        xv[r][kw] = xs[ci][r + kh][col + kw];
#pragma unroll
                for (int kw = 0; kw < 3; ++kw) {
#pragma unroll
                    for (int k = 0; k < 16; k += 4) {
                        float4 wv = *(const float4*)&wsh[ci][kh * 3 + kw][co_off + k];
#pragma unroll
                        for (int r = 0; r < 4; ++r) {
                            acc[r][k + 0] = fmaf(xv[r][kw], wv.x, acc[r][k + 0]);
                            acc[r][k + 1] = fmaf(xv[r][kw], wv.y, acc[r][k + 1]);
                            acc[r][k + 2] = fmaf(xv[r][kw], wv.z, acc[r][k + 2]);
                            acc[r][k + 3] = fmaf(xv[r][kw], wv.w, acc[r][k + 3]);
                        }
                    }
                }
            }
        }
    }
#pragma unroll
    for (int k = 0; k < 16; ++k) {
        const int co = co_base + co_off + k;
        const float bv = bias[co];
#pragma unroll
        for (int r = 0; r < 4; ++r) {
            float v = acc[r][k] + bv;
            v = v > 0.f ? v : 0.f;
            out[(((size_t)b * CC + co) * HH + (r0 + r)) * WW + col] = v;
        }
    }
}

// ---------------------------------------------------------------------------
// 1x1 heads (score + bbox) fused with anchor decode. 64-thread blocks for
// 4x the CU coverage (latency-bound kernel).
// ---------------------------------------------------------------------------
__global__ __launch_bounds__(64) void heads_decode_kernel(
    const float* __restrict__ f, const float* __restrict__ score_w,
    const float* __restrict__ score_b, const float* __restrict__ bbox_w,
    const float* __restrict__ bbox_b,
    float* __restrict__ logits, float* __restrict__ props)
{
    __shared__ float sw[CC];
    __shared__ float bw0[CC], bw1[CC], bw2[CC], bw3[CC];
    const int tid = threadIdx.x;
    for (int i = tid; i < CC; i += 64) {
        sw[i]  = score_w[i];
        bw0[i] = bbox_w[0 * CC + i];
        bw1[i] = bbox_w[1 * CC + i];
        bw2[i] = bbox_w[2 * CC + i];
        bw3[i] = bbox_w[3 * CC + i];
    }
    __syncthreads();
    const int b = blockIdx.y;
    const int n = blockIdx.x * 64 + tid;
    const float* fb = f + (size_t)b * CC * NN + n;
    float s = 0.f, d0 = 0.f, d1 = 0.f, d2 = 0.f, d3 = 0.f;
    for (int ci = 0; ci < CC; ++ci) {
        float v = fb[(size_t)ci * NN];
        s  = fmaf(v, sw[ci],  s);
        d0 = fmaf(v, bw0[ci], d0);
        d1 = fmaf(v, bw1[ci], d1);
        d2 = fmaf(v, bw2[ci], d2);
        d3 = fmaf(v, bw3[ci], d3);
    }
    s  += score_b[0];
    d0 += bbox_b[0]; d1 += bbox_b[1]; d2 += bbox_b[2]; d3 += bbox_b[3];
    logits[b * NN + n] = s;
    const int hx = n & 63, hy = n >> 6;
    const float cxa = 12.f * (float)hx, cya = 12.f * (float)hy;
    const float cx = d0 * 32.f + cxa;
    const float cy = d1 * 32.f + cya;
    const float w2 = expf(d2) * 16.f;
    const float h2 = expf(d3) * 16.f;
    float* p = props + ((size_t)b * NN + n) * 4;
    p[0] = cx - w2; p[1] = cy - h2; p[2] = cx + w2; p[3] = cy + h2;
}

// ---------------------------------------------------------------------------
// Bitonic sort on packed u64 keys (flip-encoded logit hi, NN-1-idx lo):
// numeric descending == (logit desc, idx asc) — matches lax.top_k stability.
// Then gather/clip/sigmoid/valid for top 500.
// ---------------------------------------------------------------------------
__global__ __launch_bounds__(1024) void topk_kernel(
    const float* __restrict__ logits, const float* __restrict__ props,
    float* __restrict__ props500, float* __restrict__ probs500,
    unsigned long long* __restrict__ validb)
{
    __shared__ unsigned long long skey[NN];
    const int b = blockIdx.x;
    const int tid = threadIdx.x;
    for (int i = tid; i < NN; i += 1024) {
        const unsigned u = __float_as_uint(logits[b * NN + i]);
        const unsigned k32 = u ^ ((u >> 31) ? 0xFFFFFFFFu : 0x80000000u);
        skey[i] = ((unsigned long long)k32 << 32) | (unsigned)(NN - 1 - i);
    }
    __syncthreads();
    for (int k = 2; k <= NN; k <<= 1) {
        for (int j = k >> 1; j > 0; j >>= 1) {
            for (int t = tid; t < NN / 2; t += 1024) {
                const int i = ((t & ~(j - 1)) << 1) | (t & (j - 1));
                const int l = i | j;
                const unsigned long long a = skey[i], c = skey[l];
                const bool bef  = (a > c);
                const bool swap = ((i & k) == 0) ? !bef : bef;
                if (swap) { skey[i] = c; skey[l] = a; }
            }
            __syncthreads();
        }
    }
    if (tid < 512) {   // 8 whole waves for ballot
        bool val = false;
        if (tid < TOPK) {
            const unsigned long long K = skey[tid];
            const int n = NN - 1 - (int)(K & 0xFFFFFFFFu);
            const unsigned k32 = (unsigned)(K >> 32);
            const unsigned u = (k32 & 0x80000000u) ? (k32 ^ 0x80000000u) : ~k32;
            const float v = __uint_as_float(u);
            const float* p = props + ((size_t)b * NN + n) * 4;
            const float x1 = fminf(fmaxf(p[0], 0.f), 800.f);
            const float y1 = fminf(fmaxf(p[1], 0.f), 800.f);
            const float x2 = fminf(fmaxf(p[2], 0.f), 800.f);
            const float y2 = fminf(fmaxf(p[3], 0.f), 800.f);
            const float pr = 1.f / (1.f + expf(-v));
            float* q = props500 + ((size_t)b * TOPK + tid) * 4;
            q[0] = x1; q[1] = y1; q[2] = x2; q[3] = y2;
            probs500[b * TOPK + tid] = pr;
            val = ((x2 - x1) >= 0.001f) && ((y2 - y1) >= 0.001f) && (pr >= 0.f);
        }
        const unsigned long long m = __ballot(val);
        if ((tid & 63) == 0) validb[b * 8 + (tid >> 6)] = m;
    }
}

// ---------------------------------------------------------------------------
__global__ __launch_bounds__(256) void nms_mask_kernel(
    const float* __restrict__ props500, unsigned long long* __restrict__ mask)
{
    const int gid = blockIdx.x * 256 + threadIdx.x;
    if (gid >= BB * TOPK * 8) return;
    const int wword = gid & 7;
    const int rest = gid >> 3;
    const int i = rest % TOPK;
    const int b = rest / TOPK;
    const float* bp = props500 + (size_t)b * TOPK * 4;
    const float x1 = bp[i * 4 + 0], y1 = bp[i * 4 + 1];
    const float x2 = bp[i * 4 + 2], y2 = bp[i * 4 + 3];
    const float ai = (x2 - x1) * (y2 - y1);
    unsigned long long m = 0ull;
    for (int bit = 0; bit < 64; ++bit) {
        const int j = wword * 64 + bit;
        if (j >= TOPK) break;
        if (j <= i) continue;
        const float u1 = bp[j * 4 + 0], v1 = bp[j * 4 + 1];
        const float u2 = bp[j * 4 + 2], v2 = bp[j * 4 + 3];
        const float aj = (u2 - u1) * (v2 - v1);
        const float lx = fmaxf(x1, u1), ly = fmaxf(y1, v1);
        const float rx = fminf(x2, u2), ry = fminf(y2, v2);
        const float iw = fmaxf(rx - lx, 0.f), ih = fmaxf(ry - ly, 0.f);
        const float inter = iw * ih;
        const float iou = inter / (ai + aj - inter + 1e-9f);
        if (iou > 0.7f) m |= (1ull << bit);
    }
    mask[gid] = m;
}

// ---------------------------------------------------------------------------
__global__ __launch_bounds__(256) void nms_finalize_kernel(
    const unsigned long long* __restrict__ mask,
    const unsigned long long* __restrict__ validb,
    const float* __restrict__ props500, const float* __restrict__ probs500,
    float* __restrict__ out_props, float* __restrict__ out_scores,
    float* __restrict__ out_keep)
{
    __shared__ unsigned long long sm[TOPK * 8];
    __shared__ unsigned long long sk[8];
    const int b = blockIdx.x;
    const int tid = threadIdx.x;
    for (int i = tid; i < TOPK * 8; i += 256) sm[i] = mask[(size_t)b * TOPK * 8 + i];
    if (tid < 8) sk[tid] = validb[b * 8 + tid];
    __syncthreads();
    if (tid == 0) {
        unsigned long long kw[8];
#pragma unroll
        for (int w = 0; w < 8; ++w) kw[w] = sk[w];
#pragma unroll
        for (int wi = 0; wi < 8; ++wi) {
            const int lim = (wi == 7) ? (TOPK - 7 * 64) : 64;
            for (int bi = 0; bi < lim; ++bi) {
                const unsigned long long keepbit = (kw[wi] >> bi) & 1ull;
                const unsigned long long sel = 0ull - keepbit;
                const int i = wi * 64 + bi;
#pragma unroll
                for (int w = 0; w < 8; ++w) kw[w] &= ~(sm[i * 8 + w] & sel);
            }
        }
#pragma unroll
        for (int w = 0; w < 8; ++w) sk[w] = kw[w];
    }
    __syncthreads();
    for (int t = tid; t < TOPK; t += 256) {
        const float fk = (float)((sk[t >> 6] >> (t & 63)) & 1ull);
        const float* q = props500 + ((size_t)b * TOPK + t) * 4;
        float* o = out_props + ((size_t)b * TOPK + t) * 4;
        o[0] = q[0] * fk; o[1] = q[1] * fk; o[2] = q[2] * fk; o[3] = q[3] * fk;
        out_scores[b * TOPK + t] = probs500[b * TOPK + t] * fk;
        out_keep[b * TOPK + t]   = fk;
    }
}

// ---------------------------------------------------------------------------
extern "C" void kernel_launch(void* const* d_in, const int* in_sizes, int n_in,
                              void* d_out, int out_size, void* d_ws, size_t ws_size,
                              hipStream_t stream)
{
    const float* x       = (const float*)d_in[0];
    const float* conv_w  = (const float*)d_in[1];
    const float* conv_b  = (const float*)d_in[2];
    const float* score_w = (const float*)d_in[3];
    const float* score_b = (const float*)d_in[4];
    const float* bbox_w  = (const float*)d_in[5];
    const float* bbox_b  = (const float*)d_in[6];

    float* f_out      = (float*)d_out;
    float* out_props  = f_out + (size_t)BB * CC * HH * WW;
    float* out_scores = out_props + BB * TOPK * 4;
    float* out_keep   = out_scores + BB * TOPK;

    const size_t WPE = (size_t)9 * 32 * 512 * 16;            // halves per wp buffer
    const size_t WP_BYTES = WPE * 2 * sizeof(_Float16);      // hi+lo
    const size_t SCRATCH_BYTES =
        (size_t)BB * NN * 4 + (size_t)BB * NN * 16 + (size_t)BB * TOPK * 16 +
        (size_t)BB * TOPK * 4 + (size_t)BB * 8 * 8 + (size_t)BB * TOPK * 8 * 8 + 256;
    const bool use_mfma = (ws_size >= WP_BYTES + SCRATCH_BYTES);

    _Float16* wph = (_Float16*)d_ws;
    _Float16* wpl = wph + WPE;
    char* scratch = use_mfma ? (char*)(wpl + WPE) : (char*)d_ws;

    float* logits   = (float*)scratch;
    float* props    = logits + BB * NN;
    float* props500 = props + BB * NN * 4;
    float* probs500 = props500 + BB * TOPK * 4;
    unsigned long long* validb = (unsigned long long*)(probs500 + BB * TOPK);
    unsigned long long* maskp  = validb + BB * 8;

    if (use_mfma) {
        prepack_w_kernel<<<64, 256, 0, stream>>>(conv_w, wph, wpl);
        conv3x3_mfma_kernel<<<dim3(4, 32, BB), 256, 0, stream>>>(x, wph, wpl, conv_b, f_out);
    } else {
        conv3x3_relu_kernel<<<dim3(8, 16, BB), 256, 0, stream>>>(x, conv_w, conv_b, f_out);
    }
    heads_decode_kernel<<<dim3(64, BB), 64, 0, stream>>>(f_out, score_w, score_b,
                                                         bbox_w, bbox_b, logits, props);
    topk_kernel<<<BB, 1024, 0, stream>>>(logits, props, props500, probs500, validb);
    nms_mask_kernel<<<(BB * TOPK * 8 + 255) / 256, 256, 0, stream>>>(props500, maskp);
    nms_finalize_kernel<<<BB, 256, 0, stream>>>(maskp, validb, props500, probs500,
                                                out_props, out_scores, out_keep);
}